// Round 22
// baseline (30.789 us; speedup 1.0000x reference)
//
#include <hip/hip_runtime.h>

// Delay-logistic DDE, forward Euler, d independent scalar components.
// x_{i+1} = x_i * m_i,  m_i = (1+a) - a*th1*y_i;  y_i = x(i-100) (hist = x_0).
// Output: out[j*(N+1) + t] = x_t  (row-major [d, N+1]).
//
// Round 22 = round 21 (1P+7C, flags, lgkmcnt-only fences, batched b32 drain)
// + TRUE 2-blocks/CU residency. A 512-thread block = 8 waves; 2 blocks/CU =
// 4 waves/SIMD requires VGPR <= 128. Producer h[100] costs ~130 -> r21 ran
// 3 waves/SIMD = 1.5 blocks/CU (ragged 2-generation schedule; half the
// store streams idle). Fix:
//  (a) split the delay ring: h[0..95] in VGPRs (macro-LITERAL), slots
//      96..99 in a lane-private LDS ring (ring[64][5], stride 5 dwords:
//      gcd(5,32)=1 -> conflict-free; ring reads prefetched at tile start,
//      independent of the x-chain -> latency hidden). ~119 VGPR.
//  (b) __launch_bounds__(512, 4): cap 128 (need < cap, unlike r4's collapse).
// LDS 53KB -> 2 blocks/CU -> 16 waves/CU, 14 concurrent store streams.
//
// Kept verified: zero recompute, block owns 64 rows; macro-literal h; LDS
// flag sync + lgkmcnt-only fences (vmcnt never drained in-loop; r6 lesson);
// contiguous row ranges + batched reads (r14); 7 consumers (r21); NO
// nontemporal (r19: 2.2x worse); no wide/masked store shapes (r17/18/20).

constexpr int NT   = 1000;          // N steps (setup_inputs: N=1000)
constexpr int NTAU = 100;           // delay = steps per tile
constexpr int NGRP = NT / NTAU;     // 10 tiles
constexpr int NP1  = NT + 1;        // 1001 columns per row
constexpr int COMP = 64;            // components per block (= producer lanes)
constexpr int LSTR = NTAU + 1;      // 101 dwords: odd stride -> conflict-free
constexpr int NCW  = 7;             // consumer waves
constexpr int HREG = 96;            // ring slots in VGPRs (96..99 in LDS)

// Literal-index repetition macros (SROA-proof: every h index is a literal).
#define R5(F,B)   F(B) F((B)+1) F((B)+2) F((B)+3) F((B)+4)
#define R20(F,B)  R5(F,B) R5(F,(B)+5) R5(F,(B)+10) R5(F,(B)+15)
#define R25(F,B)  R20(F,B) R5(F,(B)+20)
#define R50(F,B)  R25(F,B) R25(F,(B)+25)
#define R96(F)    R50(F,0) R25(F,50) R20(F,75) F(95)

// LDS-only ordering point: pins compiler order and drains the DS pipe.
// NEVER waits on vmcnt -> global stores keep streaming.
#define LDS_ORDER() do {                                    \
    __builtin_amdgcn_sched_barrier(0);                      \
    asm volatile("s_waitcnt lgkmcnt(0)" ::: "memory");      \
    __builtin_amdgcn_sched_barrier(0);                      \
} while (0)

__global__ __launch_bounds__(512, 4)   // 4 waves/EU target: VGPR cap 128
void ndde_kernel(const float* __restrict__ x0,
                 const float* __restrict__ tau,
                 const float* __restrict__ params,
                 float* __restrict__ out)
{
    __shared__ float buf[2][COMP][LSTR];   // 51,712 B double-buffered tile
    __shared__ float ring[COMP][5];        // 1,280 B: ring slots 96..99 (+pad)
    __shared__ int   prodf;                // tiles staged by producer
    __shared__ int   consf[NCW];           // tiles consumed, per consumer wave
    const int tid  = threadIdx.x;
    const int wid  = tid >> 6;             // 0 = producer, 1..7 = consumers
    const int lane = tid & 63;
    const int jbase = (int)blockIdx.x * COMP;

    const float dt = 0.01f * tau[0];
    const float a  = dt * params[0];        // dt * theta0
    const float q  = -(a * params[1]);      // -dt*theta0*theta1
    const float p  = 1.0f + a;

    if (tid < NCW + 1) {                    // init flags
        if (tid == 0) prodf = 0;
        else consf[tid - 1] = 0;
    }
    __syncthreads();                        // flag init only (once; queues empty)

    volatile int* vprod = &prodf;
    volatile int* vcons = consf;

    if (wid == 0) {
        // ---------------- producer ----------------
        float x = x0[jbase + lane];
        float h[HREG];                      // ring slots 0..95 (VGPRs)
#define INIT_H(K) h[(K)] = x;
        R96(INIT_H)
        ring[lane][0] = x; ring[lane][1] = x;   // slots 96..99 = history x_0
        ring[lane][2] = x; ring[lane][3] = x;

#define STEP(K) { const float y_ = h[(K)]; h[(K)] = x; x *= fmaf(q, y_, p); }
#define STG(K)  bp[(K)] = h[(K)];

#pragma clang loop unroll(disable)          // keep ~320-instr body I-cache-resident
        for (int g = 0; g < NGRP; ++g) {
            if (g >= 2) {                   // buf[g&1] holds tile g-2: wait consumed
                for (;;) {
                    int done = 1;
#pragma unroll
                    for (int c = 0; c < NCW; ++c)
                        if (vcons[c] < g - 1) done = 0;
                    if (done) break;
                    __builtin_amdgcn_s_sleep(1);
                }
                LDS_ORDER();                // poll -> overwrite (cross-wave WAR)
            }
            // Prefetch ring slots (x_{100(g-1)+96..99}); independent of x-chain.
            const float y96 = ring[lane][0], y97 = ring[lane][1];
            const float y98 = ring[lane][2], y99 = ring[lane][3];
            R96(STEP)                       // steps k=0..95: h[k] = x_{100g+k}
            float* bp = &buf[g & 1][lane][0];
            R96(STG)                        // stage reg part (stride-101: clean)
            // Steps k=96..99 via LDS ring; stage directly while at it.
            ring[lane][0] = x; bp[96] = x; x *= fmaf(q, y96, p);
            ring[lane][1] = x; bp[97] = x; x *= fmaf(q, y97, p);
            ring[lane][2] = x; bp[98] = x; x *= fmaf(q, y98, p);
            ring[lane][3] = x; bp[99] = x; x *= fmaf(q, y99, p);
            LDS_ORDER();                    // data writes drain before flag (RAW)
            *vprod = g + 1;                 // publish tile g
        }
        // Final column t = N: x = x_1000.
        out[(size_t)(jbase + lane) * NP1 + NT] = x;
    } else {
        // ---------------- consumers ----------------
        const int cw    = wid - 1;                       // 0..6
        const int start = (cw == 0) ? 0 : 10 + 9 * (cw - 1);
        const int cnt   = (cw == 0) ? 10 : 9;            // 10 + 6*9 = 64
        const int lane2 = (lane < 36) ? lane : 35;       // clamp: no LDS OOB
        float* gpb = out + (jbase + start) * NP1 + lane; // row-contiguous range

#pragma clang loop unroll(disable)
        for (int g = 0; g < NGRP; ++g) {
            while (*vprod < g + 1)          // wait for tile g
                __builtin_amdgcn_s_sleep(1);
            LDS_ORDER();                    // poll -> data reads (cross-wave RAW)
            const float* bb = &buf[g & 1][start][0];
            float* gp = gpb + g * NTAU;

            // Batch all rows' reads (<=20 regs), then all stores in address
            // order (one lgkm wait per tile; stores stream, never vmcnt-waited).
            float va[10], vb[10];
#pragma unroll
            for (int i = 0; i < 10; ++i) {
                if (i < cnt) {
                    va[i] = bb[i * LSTR + lane];
                    vb[i] = bb[i * LSTR + 64 + lane2];
                }
            }
#pragma unroll
            for (int i = 0; i < 10; ++i) {
                if (i < cnt) {
                    float* rp = gp + i * NP1;
                    rp[0] = va[i];                        // t = 100g + 0..63
                    if (lane < NTAU - 64) rp[64] = vb[i]; // t = 100g + 64..99
                }
            }
            LDS_ORDER();                    // ds_reads drained (stores NOT waited)
            vcons[cw] = g + 1;              // release buf[g&1]
        }
    }
}

extern "C" void kernel_launch(void* const* d_in, const int* in_sizes, int n_in,
                              void* d_out, int out_size, void* d_ws, size_t ws_size,
                              hipStream_t stream) {
    const float* x0     = (const float*)d_in[0];
    const float* tau    = (const float*)d_in[1];
    const float* params = (const float*)d_in[2];
    float* out = (float*)d_out;
    const int d = in_sizes[0];              // 32768
    const int nblocks = d / COMP;           // 512 blocks x 512 threads
    ndde_kernel<<<nblocks, 512, 0, stream>>>(x0, tau, params, out);
}